// Round 1
// baseline (573.821 us; speedup 1.0000x reference)
//
#include <hip/hip_runtime.h>

#define C_DIM 128
#define HW_DIM 6144

typedef __attribute__((ext_vector_type(8))) short short8;
typedef __attribute__((ext_vector_type(4))) float f32x4;

static __device__ __forceinline__ unsigned short f2bf(float x) {
    unsigned int u = __builtin_bit_cast(unsigned int, x);
    u = (u + 0x7FFFu + ((u >> 16) & 1u)) >> 16;
    return (unsigned short)u;
}
static __device__ __forceinline__ float bf2f(unsigned short u) {
    unsigned int x = ((unsigned int)u) << 16;
    return __builtin_bit_cast(float, x);
}
static __device__ __forceinline__ unsigned int pack2(float a, float b) {
    return (unsigned int)f2bf(a) | ((unsigned int)f2bf(b) << 16);
}
static __device__ __forceinline__ f32x4 mfma_bf16(short8 a, short8 b, f32x4 c) {
    return __builtin_amdgcn_mfma_f32_16x16x32_bf16(a, b, c, 0, 0, 0);
}

// ---------------------------------------------------------------------------
// MFMA 1x1-conv + BN + LeakyReLU. M=128 out-ch, N=64 positions/block, K=128.
// W and X staged to LDS as bf16 with the flash-verified XOR chunk swizzle.
// in_mode : 0 = X fp32 [b][c][hw] (transpose-stage)
//           1 = X bf16 [b][pos][c] (direct stage)
//           2 = combine: sum of nparts partials [pos][c] bf16 * invL[pos]
// out_mode: 0 = bf16 [b][pos][c] * oscale (via LDS transpose, coalesced)
//           1 = bf16 [b][c][pos]          (via LDS transpose, coalesced)
//           2 = fp32 [b][c][hw] + residual (direct from C frags)
// r15: in_mode 2 generalized to nparts partials at fixed stride (supports
// 8-way flash split-K).
// ---------------------------------------------------------------------------
struct MJob {
    const void* X;          // input (or P-partials base for in_mode 2)
    const float* L;         // L-partials base (in_mode 2)
    const float* W; const float* G; const float* B;
    void* out; const float* resid;
    float oscale; int in_mode; int out_mode; int nparts;
};
struct MJobs { MJob j[3]; };

__global__ __launch_bounds__(256)
void conv_mfma(MJobs jobs)
{
    const MJob jb = (blockIdx.z == 0) ? jobs.j[0]
                  : (blockIdx.z == 1) ? jobs.j[1] : jobs.j[2];

    __shared__ __align__(16) unsigned short Wt[128 * 128];  // 32 KB [o][c]
    __shared__ __align__(16) unsigned short Xt[64 * 128];   // 16 KB [p][c]
    __shared__ __align__(16) unsigned short Ct[128 * 64];   // 16 KB epilogue
    __shared__ float invl[64];

    const int t    = threadIdx.x;
    const int b    = blockIdx.y;
    const int p0   = blockIdx.x * 64;
    const int wave = t >> 6;
    const int lane = t & 63;
    const int quad = lane >> 4;
    const int l16  = lane & 15;

    // ---- stage W: fp32 [o][c] -> bf16 Wt[o][chunk^(o&15)] ----
    const float* Wg = jb.W;
#pragma unroll
    for (int i = 0; i < 16; ++i) {
        int f = i * 1024 + t * 4;             // o = f>>7, c = f&127 (mult of 4)
        int o = f >> 7, c = f & 127;
        float4 w4 = *(const float4*)&Wg[o * C_DIM + c];
        int addr = o * 128 + (((c >> 3) ^ (o & 15)) * 8) + (c & 7);
        *(unsigned int*)&Wt[addr]     = pack2(w4.x, w4.y);
        *(unsigned int*)&Wt[addr + 2] = pack2(w4.z, w4.w);
    }

    // ---- stage X per in_mode -> bf16 Xt[p][chunk^(p&15)] ----
    if (jb.in_mode == 0) {
        const float* Xg = (const float*)jb.X + (size_t)b * C_DIM * HW_DIM;
#pragma unroll
        for (int i = 0; i < 8; ++i) {
            int f = i * 1024 + t * 4;         // c = f>>6, p = f&63 (mult of 4)
            int c = f >> 6, p = f & 63;
            float4 x4 = *(const float4*)&Xg[(size_t)c * HW_DIM + p0 + p];
            float xv[4] = {x4.x, x4.y, x4.z, x4.w};
#pragma unroll
            for (int j = 0; j < 4; ++j) {
                int pp = p + j;
                Xt[pp * 128 + (((c >> 3) ^ (pp & 15)) * 8) + (c & 7)] = f2bf(xv[j]);
            }
        }
    } else if (jb.in_mode == 1) {
        const unsigned short* Xg = (const unsigned short*)jb.X;
#pragma unroll
        for (int i = 0; i < 4; ++i) {
            int idx = t + 256 * i;            // p = idx>>4, ch = idx&15
            int p = idx >> 4, ch = idx & 15;
            uint4 v = *(const uint4*)&Xg[((size_t)b * HW_DIM + p0 + p) * C_DIM + ch * 8];
            *(uint4*)&Xt[p * 128 + ((ch ^ (p & 15)) * 8)] = v;
        }
    } else {
        if (t < 64) {
            size_t li = (size_t)b * HW_DIM + p0 + t;
            float s = 0.f;
            for (int pr = 0; pr < jb.nparts; ++pr)
                s += jb.L[li + (size_t)pr * (2 * HW_DIM)];
            invl[t] = 1.0f / s;
        }
        __syncthreads();
        const unsigned short* A0 = (const unsigned short*)jb.X;
        const size_t pstride = (size_t)2 * HW_DIM * C_DIM;   // ushorts per part
#pragma unroll
        for (int i = 0; i < 4; ++i) {
            int idx = t + 256 * i;
            int p = idx >> 4, ch = idx & 15;
            size_t gi = ((size_t)b * HW_DIM + p0 + p) * C_DIM + ch * 8;
            float acc8[8] = {0.f, 0.f, 0.f, 0.f, 0.f, 0.f, 0.f, 0.f};
            for (int pr = 0; pr < jb.nparts; ++pr) {
                uint4 a = *(const uint4*)&A0[gi + (size_t)pr * pstride];
                const unsigned int* ap = (const unsigned int*)&a;
#pragma unroll
                for (int j = 0; j < 4; ++j) {
                    acc8[2 * j]     += bf2f((unsigned short)(ap[j] & 0xFFFF));
                    acc8[2 * j + 1] += bf2f((unsigned short)(ap[j] >> 16));
                }
            }
            float s = invl[p];
            unsigned int w[4];
#pragma unroll
            for (int j = 0; j < 4; ++j)
                w[j] = pack2(acc8[2 * j] * s, acc8[2 * j + 1] * s);
            *(uint4*)&Xt[p * 128 + ((ch ^ (p & 15)) * 8)] = *(uint4*)w;
        }
    }
    __syncthreads();

    // ---- MFMA: wave handles m-tiles {2w, 2w+1} x 4 n-tiles, K=128 ----
    short8 af[2][4];
#pragma unroll
    for (int mi = 0; mi < 2; ++mi)
#pragma unroll
        for (int s = 0; s < 4; ++s)
            af[mi][s] = *(const short8*)
                &Wt[((wave * 2 + mi) * 16 + l16) * 128 + (((4 * s + quad) ^ l16) * 8)];

    f32x4 acc[2][4];
#pragma unroll
    for (int mi = 0; mi < 2; ++mi)
#pragma unroll
        for (int nt = 0; nt < 4; ++nt) acc[mi][nt] = (f32x4){0.f, 0.f, 0.f, 0.f};
#pragma unroll
    for (int nt = 0; nt < 4; ++nt)
#pragma unroll
        for (int s = 0; s < 4; ++s) {
            short8 bf = *(const short8*)
                &Xt[(nt * 16 + l16) * 128 + (((4 * s + quad) ^ l16) * 8)];
            acc[0][nt] = mfma_bf16(af[0][s], bf, acc[0][nt]);
            acc[1][nt] = mfma_bf16(af[1][s], bf, acc[1][nt]);
        }

    // ---- BN + LeakyReLU on C fragments (row o = mt*16+quad*4+r, col l16) ----
    const float BNRS = 0.99999500003749972f;  // 1/sqrt(1 + 1e-5)
#pragma unroll
    for (int mi = 0; mi < 2; ++mi)
#pragma unroll
        for (int r = 0; r < 4; ++r) {
            int o = (wave * 2 + mi) * 16 + quad * 4 + r;
            float sc = jb.G[o] * BNRS, bb = jb.B[o];
#pragma unroll
            for (int nt = 0; nt < 4; ++nt) {
                float y = fmaf(acc[mi][nt][r], sc, bb);
                acc[mi][nt][r] = y > 0.f ? y : 0.1f * y;
            }
        }

    // ---- epilogue ----
    if (jb.out_mode == 0) {
        // bf16 [b][pos][c] * oscale, via Ct[p][o-chunk^(p&15)]
        unsigned short* O = (unsigned short*)jb.out;
        float os = jb.oscale;
#pragma unroll
        for (int mi = 0; mi < 2; ++mi)
#pragma unroll
            for (int nt = 0; nt < 4; ++nt)
#pragma unroll
                for (int r = 0; r < 4; ++r) {
                    int o = (wave * 2 + mi) * 16 + quad * 4 + r;
                    int p = nt * 16 + l16;
                    Ct[p * 128 + (((o >> 3) ^ (p & 15)) * 8) + (o & 7)] =
                        f2bf(acc[mi][nt][r] * os);
                }
        __syncthreads();
#pragma unroll
        for (int i = 0; i < 4; ++i) {
            int idx = t + 256 * i;
            int p = idx >> 4, ch = idx & 15;
            uint4 v = *(const uint4*)&Ct[p * 128 + ((ch ^ (p & 15)) * 8)];
            *(uint4*)&O[((size_t)b * HW_DIM + p0 + p) * C_DIM + ch * 8] = v;
        }
    } else if (jb.out_mode == 1) {
        // bf16 [b][c][pos], via Ct[o][p-chunk^(o&7)]
        unsigned short* O = (unsigned short*)jb.out;
#pragma unroll
        for (int mi = 0; mi < 2; ++mi)
#pragma unroll
            for (int nt = 0; nt < 4; ++nt)
#pragma unroll
                for (int r = 0; r < 4; ++r) {
                    int o = (wave * 2 + mi) * 16 + quad * 4 + r;
                    int p = nt * 16 + l16;
                    Ct[o * 64 + (((p >> 3) ^ (o & 7)) * 8) + (p & 7)] =
                        f2bf(acc[mi][nt][r]);
                }
        __syncthreads();
#pragma unroll
        for (int i = 0; i < 4; ++i) {          // all 1024 chunks (r14 fix kept)
            int idx = t + 256 * i;
            int o = idx >> 3, ch = idx & 7;
            uint4 v = *(const uint4*)&Ct[o * 64 + ((ch ^ (o & 7)) * 8)];
            *(uint4*)&O[((size_t)b * C_DIM + o) * HW_DIM + p0 + ch * 8] = v;
        }
    } else {
        // fp32 [b][c][hw] + residual, direct
        float* O = (float*)jb.out;
#pragma unroll
        for (int mi = 0; mi < 2; ++mi)
#pragma unroll
            for (int nt = 0; nt < 4; ++nt)
#pragma unroll
                for (int r = 0; r < 4; ++r) {
                    int o = (wave * 2 + mi) * 16 + quad * 4 + r;
                    size_t g = ((size_t)b * C_DIM + o) * HW_DIM + p0 + nt * 16 + l16;
                    O[g] = acc[mi][nt][r] + jb.resid[g];
                }
    }
}

// ---------------------------------------------------------------------------
// Flash attention (r15): templated on NSPLIT-way global split-K.
// 512 thr = 2 wave-groups of 4; groups split the block's k-slice in half with
// own swizzled tiles; rt=3 row-tiles/wave; internal group combine.
// r15 changes vs r13/r14:
//  - Plds [8][16][72] -> [8][16][64] + XOR chunk swizzle: LDS drops
//    83968 -> 81920 B (exactly 80 KB) so TWO blocks fit per CU.
//  - NSPLIT=8 path: 512 blocks = 4096 waves = 4 waves/SIMD (was 2) for
//    latency hiding; NIT halves to 6. NSPLIT=4 path is byte-equivalent to
//    r13 (fallback when workspace < 35 MB).
//  - __launch_bounds__(512,4) pins VGPR <= 128 (it already was 128).
// ---------------------------------------------------------------------------
template <int NSPLIT>
__global__ __launch_bounds__(512, 4)
void flash_attn(const unsigned short* __restrict__ Q,
                const unsigned short* __restrict__ K,
                const unsigned short* __restrict__ V,
                unsigned short* __restrict__ Pbase,
                float* __restrict__ Lbase)
{
    __shared__ __align__(16) unsigned short TM[2][16384];     // 64 KB
    __shared__ __align__(16) unsigned short Plds[8][16][64];  // 16 KB (swizzled)
    const int tid  = threadIdx.x;
    const int wave = tid >> 6;
    const int gid  = wave >> 2;
    const int wl   = wave & 3;
    const int gtid = tid & 255;
    const int lane = tid & 63;
    const int quad = lane >> 4;
    const int l16  = lane & 15;

    const int bid  = blockIdx.x;
    const int xcd  = bid & 7;
    const int b    = xcd >> 2;
    const int g3   = xcd & 3;
    const int i    = bid >> 3;                 // 0 .. 8*NSPLIT-1
    const int ks   = i >> 3;                   // 0 .. NSPLIT-1
    const int qblk = g3 * 8 + (i & 7);         // 0 .. 31
    const int q0   = qblk * 192 + wl * 48;
    const int kbeg = ks * (HW_DIM / NSPLIT) + gid * (HW_DIM / (2 * NSPLIT));

    unsigned short* __restrict__ Po = Pbase + (size_t)ks * (2 * HW_DIM * C_DIM);
    float* __restrict__ Lo          = Lbase + (size_t)ks * (2 * HW_DIM);

    const unsigned short* Qb = Q + (size_t)b * HW_DIM * C_DIM;
    const unsigned short* Kb = K + (size_t)b * HW_DIM * C_DIM;
    const unsigned short* Vb = V + (size_t)b * C_DIM * HW_DIM;

    unsigned short* Kt = TM[gid];
    unsigned short* Vt = TM[gid] + 8192;

    short8 qf[3][4];
#pragma unroll
    for (int rt = 0; rt < 3; ++rt)
#pragma unroll
        for (int s = 0; s < 4; ++s)
            qf[rt][s] = *(const short8*)
                &Qb[(size_t)(q0 + rt * 16 + l16) * C_DIM + s * 32 + quad * 8];

    f32x4 O[3][8];
#pragma unroll
    for (int rt = 0; rt < 3; ++rt)
#pragma unroll
        for (int h = 0; h < 8; ++h) O[rt][h] = (f32x4){0.f, 0.f, 0.f, 0.f};
    float lsum[3][4] = {{0,0,0,0},{0,0,0,0},{0,0,0,0}};

    uint4 kst[4], vst[4];
#pragma unroll
    for (int j = 0; j < 4; ++j) {
        int ck = gtid + 256 * j;
        kst[j] = *(const uint4*)&Kb[(size_t)(kbeg + (ck >> 4)) * C_DIM + (ck & 15) * 8];
        vst[j] = *(const uint4*)&Vb[(size_t)(ck >> 3) * HW_DIM + kbeg + (ck & 7) * 8];
    }

    const int NIT = (HW_DIM / (2 * NSPLIT)) / 64;   // 12 (NSPLIT=4) or 6 (=8)
    for (int it = 0; it < NIT; ++it) {
#pragma unroll
        for (int j = 0; j < 4; ++j) {
            int ck = gtid + 256 * j;
            *(uint4*)&Kt[(size_t)(ck >> 4) * 128 + (((ck & 15) ^ ((ck >> 4) & 15)) * 8)] = kst[j];
            *(uint4*)&Vt[(size_t)(ck >> 3) * 64 + (((ck & 7) ^ ((ck >> 3) & 7)) * 8)]   = vst[j];
        }
        __syncthreads();

        if (it + 1 < NIT) {
            const int kb2 = kbeg + (it + 1) * 64;
#pragma unroll
            for (int j = 0; j < 4; ++j) {
                int ck = gtid + 256 * j;
                kst[j] = *(const uint4*)
                    &Kb[(size_t)(kb2 + (ck >> 4)) * C_DIM + (ck & 15) * 8];
                vst[j] = *(const uint4*)
                    &Vb[(size_t)(ck >> 3) * HW_DIM + kb2 + (ck & 7) * 8];
            }
        }

        f32x4 S[3][4];
#pragma unroll
        for (int rt = 0; rt < 3; ++rt)
#pragma unroll
            for (int n = 0; n < 4; ++n) S[rt][n] = (f32x4){0.f, 0.f, 0.f, 0.f};
#pragma unroll
        for (int n = 0; n < 4; ++n)
#pragma unroll
            for (int s = 0; s < 4; ++s) {
                short8 kf = *(const short8*)
                    &Kt[(size_t)(n * 16 + l16) * 128 + (((4 * s + quad) ^ l16) * 8)];
                S[0][n] = mfma_bf16(qf[0][s], kf, S[0][n]);
                S[1][n] = mfma_bf16(qf[1][s], kf, S[1][n]);
                S[2][n] = mfma_bf16(qf[2][s], kf, S[2][n]);
            }

        // P round-trip through swizzled Plds: logical [row=quad*4+r][col=n*16+l16],
        // physical chunk = (col>>3) ^ (row&7). Reads below use matching XOR.
        short8 pa[3][2];
#pragma unroll
        for (int rt = 0; rt < 3; ++rt) {
#pragma unroll
            for (int n = 0; n < 4; ++n)
#pragma unroll
                for (int r = 0; r < 4; ++r) {
                    float e = __builtin_amdgcn_exp2f(S[rt][n][r]);
                    lsum[rt][r] += e;
                    int row = quad * 4 + r;
                    Plds[wave][row][(((n * 2 + (l16 >> 3)) ^ (row & 7)) << 3) | (l16 & 7)] =
                        f2bf(e);
                }
            pa[rt][0] = *(const short8*)&Plds[wave][l16][((quad     ^ (l16 & 7)) << 3)];
            pa[rt][1] = *(const short8*)&Plds[wave][l16][(((4 + quad) ^ (l16 & 7)) << 3)];
        }

        const int m = l16 & 7;
#pragma unroll
        for (int h = 0; h < 8; ++h) {
            short8 v0 = *(const short8*)&Vt[(size_t)(h * 16 + l16) * 64 + ((quad ^ m) * 8)];
            short8 v1 = *(const short8*)&Vt[(size_t)(h * 16 + l16) * 64 + (((quad + 4) ^ m) * 8)];
            O[0][h] = mfma_bf16(pa[0][0], v0, O[0][h]);
            O[0][h] = mfma_bf16(pa[0][1], v1, O[0][h]);
            O[1][h] = mfma_bf16(pa[1][0], v0, O[1][h]);
            O[1][h] = mfma_bf16(pa[1][1], v1, O[1][h]);
            O[2][h] = mfma_bf16(pa[2][0], v0, O[2][h]);
            O[2][h] = mfma_bf16(pa[2][1], v1, O[2][h]);
        }
        __syncthreads();
    }

#pragma unroll
    for (int off = 1; off < 16; off <<= 1)
#pragma unroll
        for (int rt = 0; rt < 3; ++rt)
#pragma unroll
            for (int r = 0; r < 4; ++r)
                lsum[rt][r] += __shfl_xor(lsum[rt][r], off, 64);

    unsigned short* CB = &TM[0][0];
    float* Lsh = (float*)&Plds[0][0][0];
    __syncthreads();
    if (gid == 1) {
#pragma unroll
        for (int rt = 0; rt < 3; ++rt)
#pragma unroll
            for (int r = 0; r < 4; ++r) {
                int lrow = wl * 48 + rt * 16 + quad * 4 + r;
                if (l16 == 0) Lsh[lrow] = lsum[rt][r];
#pragma unroll
                for (int h = 0; h < 8; ++h)
                    CB[lrow * 132 + h * 16 + l16] = f2bf(O[rt][h][r]);
            }
    }
    __syncthreads();
    if (gid == 0) {
#pragma unroll
        for (int rt = 0; rt < 3; ++rt)
#pragma unroll
            for (int r = 0; r < 4; ++r) {
                int lrow = wl * 48 + rt * 16 + quad * 4 + r;
                size_t row = (size_t)b * HW_DIM + qblk * 192 + lrow;
                if (l16 == 0) Lo[row] = lsum[rt][r] + Lsh[lrow];
#pragma unroll
                for (int h = 0; h < 8; ++h) {
                    float s = O[rt][h][r] + bf2f(CB[lrow * 132 + h * 16 + l16]);
                    Po[row * C_DIM + h * 16 + l16] = f2bf(s);
                }
            }
    }
}

// ---------------------------------------------------------------------------
extern "C" void kernel_launch(void* const* d_in, const int* in_sizes, int n_in,
                              void* d_out, int out_size, void* d_ws, size_t ws_size,
                              hipStream_t stream)
{
    const float* query = (const float*)d_in[0];
    const float* key   = (const float*)d_in[1];
    const float* q_w1 = (const float*)d_in[2];
    const float* q_g1 = (const float*)d_in[3];
    const float* q_b1 = (const float*)d_in[4];
    const float* q_w2 = (const float*)d_in[5];
    const float* q_g2 = (const float*)d_in[6];
    const float* q_b2 = (const float*)d_in[7];
    const float* k_w1 = (const float*)d_in[8];
    const float* k_g1 = (const float*)d_in[9];
    const float* k_b1 = (const float*)d_in[10];
    const float* k_w2 = (const float*)d_in[11];
    const float* k_g2 = (const float*)d_in[12];
    const float* k_b2 = (const float*)d_in[13];
    const float* v_w  = (const float*)d_in[14];
    const float* v_g  = (const float*)d_in[15];
    const float* v_b  = (const float*)d_in[16];
    const float* o_w  = (const float*)d_in[17];
    const float* o_g  = (const float*)d_in[18];
    const float* o_b  = (const float*)d_in[19];

    // Workspace layout (contiguous):
    //   [ P partials: nsplit x 3145728 B ][ Qbf ][ Kbf ][ Vbf ][ L: nsplit x 49152 B ]
    // nsplit=8 needs 34,996,224 B; nsplit=4 needs 22,216,704 B (== r13/r14 usage,
    // guaranteed to fit since the previous layout passed). Qmid/Kmid alias
    // P-partials 0/1 (dead before flash writes them).
    const size_t PPART = (size_t)2 * HW_DIM * C_DIM * 2;  // 3,145,728 B
    const size_t LPART = (size_t)2 * HW_DIM * 4;          // 49,152 B
    const int nsplit = (ws_size >= 11 * PPART + 8 * LPART) ? 8 : 4;

    char* ws = (char*)d_ws;
    unsigned short* Pbase = (unsigned short*)ws;
    unsigned short* Qbf = (unsigned short*)(ws + (size_t)nsplit * PPART);
    unsigned short* Kbf = (unsigned short*)(ws + (size_t)nsplit * PPART + PPART);
    unsigned short* Vbf = (unsigned short*)(ws + (size_t)nsplit * PPART + 2 * PPART);
    float*          Lbase = (float*)(ws + (size_t)nsplit * PPART + 3 * PPART);
    unsigned short* Qmid = Pbase;                       // aliases partial 0
    unsigned short* Kmid = Pbase + PPART / 2;           // aliases partial 1
    float* outp = (float*)d_out;

    const float qscale = 0.08838834764831845f * 1.44269504088896340f;

    // Launch A: q-conv1 -> Qmid, k-conv1 -> Kmid, v-conv -> Vbf.
    {
        MJobs J{};
        J.j[0] = {query, nullptr, q_w1, q_g1, q_b1, (void*)Qmid, nullptr, 1.0f, 0, 0, 0};
        J.j[1] = {key,   nullptr, k_w1, k_g1, k_b1, (void*)Kmid, nullptr, 1.0f, 0, 0, 0};
        J.j[2] = {key,   nullptr, v_w,  v_g,  v_b,  (void*)Vbf,  nullptr, 1.0f, 0, 1, 0};
        hipLaunchKernelGGL(conv_mfma, dim3(HW_DIM / 64, 2, 3), dim3(256),
                           0, stream, J);
    }
    // Launch B: q-conv2 -> Qbf (scaled), k-conv2 -> Kbf.
    {
        MJobs J{};
        J.j[0] = {Qmid, nullptr, q_w2, q_g2, q_b2, (void*)Qbf, nullptr, qscale, 1, 0, 0};
        J.j[1] = {Kmid, nullptr, k_w2, k_g2, k_b2, (void*)Kbf, nullptr, 1.0f,   1, 0, 0};
        J.j[2] = J.j[1];
        hipLaunchKernelGGL(conv_mfma, dim3(HW_DIM / 64, 2, 2), dim3(256),
                           0, stream, J);
    }

    // Flash: NSPLIT-way global split-K, 64*NSPLIT blocks.
    if (nsplit == 8) {
        hipLaunchKernelGGL(HIP_KERNEL_NAME(flash_attn<8>), dim3(512), dim3(512),
                           0, stream, Qbf, Kbf, Vbf, Pbase, Lbase);
    } else {
        hipLaunchKernelGGL(HIP_KERNEL_NAME(flash_attn<4>), dim3(256), dim3(512),
                           0, stream, Qbf, Kbf, Vbf, Pbase, Lbase);
    }

    // Launch C: combine nsplit partials -> out-conv + residual.
    {
        MJobs J{};
        J.j[0] = {Pbase, Lbase, o_w, o_g, o_b, (void*)outp, query, 1.0f, 2, 2, nsplit};
        J.j[1] = J.j[0];
        J.j[2] = J.j[0];
        hipLaunchKernelGGL(conv_mfma, dim3(HW_DIM / 64, 2, 1), dim3(256),
                           0, stream, J);
    }
}

// Round 2
// 186.545 us; speedup vs baseline: 3.0760x; 3.0760x over previous
//
#include <hip/hip_runtime.h>

#define C_DIM 128
#define HW_DIM 6144

typedef __attribute__((ext_vector_type(8))) short short8;
typedef __attribute__((ext_vector_type(4))) float f32x4;

static __device__ __forceinline__ unsigned short f2bf(float x) {
    unsigned int u = __builtin_bit_cast(unsigned int, x);
    u = (u + 0x7FFFu + ((u >> 16) & 1u)) >> 16;
    return (unsigned short)u;
}
static __device__ __forceinline__ float bf2f(unsigned short u) {
    unsigned int x = ((unsigned int)u) << 16;
    return __builtin_bit_cast(float, x);
}
static __device__ __forceinline__ unsigned int pack2(float a, float b) {
    return (unsigned int)f2bf(a) | ((unsigned int)f2bf(b) << 16);
}
static __device__ __forceinline__ f32x4 mfma_bf16(short8 a, short8 b, f32x4 c) {
    return __builtin_amdgcn_mfma_f32_16x16x32_bf16(a, b, c, 0, 0, 0);
}
// async global->LDS, 16B per lane; LDS dest is wave-uniform-base + lane*16,
// global source is per-lane (pre-swizzled).
static __device__ __forceinline__ void gload16(const unsigned short* g,
                                               unsigned short* l) {
    __builtin_amdgcn_global_load_lds(
        (const __attribute__((address_space(1))) unsigned int*)g,
        (__attribute__((address_space(3))) unsigned int*)l, 16, 0, 0);
}

// ---------------------------------------------------------------------------
// MFMA 1x1-conv + BN + LeakyReLU. M=128 out-ch, N=64 positions/block, K=128.
// (unchanged from r15 — proven correct)
// in_mode : 0 = X fp32 [b][c][hw] (transpose-stage)
//           1 = X bf16 [b][pos][c] (direct stage)
//           2 = combine: sum of nparts partials [pos][c] bf16 * invL[pos]
// out_mode: 0 = bf16 [b][pos][c] * oscale
//           1 = bf16 [b][c][pos]
//           2 = fp32 [b][c][hw] + residual
// ---------------------------------------------------------------------------
struct MJob {
    const void* X;          // input (or P-partials base for in_mode 2)
    const float* L;         // L-partials base (in_mode 2)
    const float* W; const float* G; const float* B;
    void* out; const float* resid;
    float oscale; int in_mode; int out_mode; int nparts;
};
struct MJobs { MJob j[3]; };

__global__ __launch_bounds__(256)
void conv_mfma(MJobs jobs)
{
    const MJob jb = (blockIdx.z == 0) ? jobs.j[0]
                  : (blockIdx.z == 1) ? jobs.j[1] : jobs.j[2];

    __shared__ __align__(16) unsigned short Wt[128 * 128];  // 32 KB [o][c]
    __shared__ __align__(16) unsigned short Xt[64 * 128];   // 16 KB [p][c]
    __shared__ __align__(16) unsigned short Ct[128 * 64];   // 16 KB epilogue
    __shared__ float invl[64];

    const int t    = threadIdx.x;
    const int b    = blockIdx.y;
    const int p0   = blockIdx.x * 64;
    const int wave = t >> 6;
    const int lane = t & 63;
    const int quad = lane >> 4;
    const int l16  = lane & 15;

    // ---- stage W: fp32 [o][c] -> bf16 Wt[o][chunk^(o&15)] ----
    const float* Wg = jb.W;
#pragma unroll
    for (int i = 0; i < 16; ++i) {
        int f = i * 1024 + t * 4;             // o = f>>7, c = f&127 (mult of 4)
        int o = f >> 7, c = f & 127;
        float4 w4 = *(const float4*)&Wg[o * C_DIM + c];
        int addr = o * 128 + (((c >> 3) ^ (o & 15)) * 8) + (c & 7);
        *(unsigned int*)&Wt[addr]     = pack2(w4.x, w4.y);
        *(unsigned int*)&Wt[addr + 2] = pack2(w4.z, w4.w);
    }

    // ---- stage X per in_mode -> bf16 Xt[p][chunk^(p&15)] ----
    if (jb.in_mode == 0) {
        const float* Xg = (const float*)jb.X + (size_t)b * C_DIM * HW_DIM;
#pragma unroll
        for (int i = 0; i < 8; ++i) {
            int f = i * 1024 + t * 4;         // c = f>>6, p = f&63 (mult of 4)
            int c = f >> 6, p = f & 63;
            float4 x4 = *(const float4*)&Xg[(size_t)c * HW_DIM + p0 + p];
            float xv[4] = {x4.x, x4.y, x4.z, x4.w};
#pragma unroll
            for (int j = 0; j < 4; ++j) {
                int pp = p + j;
                Xt[pp * 128 + (((c >> 3) ^ (pp & 15)) * 8) + (c & 7)] = f2bf(xv[j]);
            }
        }
    } else if (jb.in_mode == 1) {
        const unsigned short* Xg = (const unsigned short*)jb.X;
#pragma unroll
        for (int i = 0; i < 4; ++i) {
            int idx = t + 256 * i;            // p = idx>>4, ch = idx&15
            int p = idx >> 4, ch = idx & 15;
            uint4 v = *(const uint4*)&Xg[((size_t)b * HW_DIM + p0 + p) * C_DIM + ch * 8];
            *(uint4*)&Xt[p * 128 + ((ch ^ (p & 15)) * 8)] = v;
        }
    } else {
        if (t < 64) {
            size_t li = (size_t)b * HW_DIM + p0 + t;
            float s = 0.f;
            for (int pr = 0; pr < jb.nparts; ++pr)
                s += jb.L[li + (size_t)pr * (2 * HW_DIM)];
            invl[t] = 1.0f / s;
        }
        __syncthreads();
        const unsigned short* A0 = (const unsigned short*)jb.X;
        const size_t pstride = (size_t)2 * HW_DIM * C_DIM;   // ushorts per part
#pragma unroll
        for (int i = 0; i < 4; ++i) {
            int idx = t + 256 * i;
            int p = idx >> 4, ch = idx & 15;
            size_t gi = ((size_t)b * HW_DIM + p0 + p) * C_DIM + ch * 8;
            float acc8[8] = {0.f, 0.f, 0.f, 0.f, 0.f, 0.f, 0.f, 0.f};
            for (int pr = 0; pr < jb.nparts; ++pr) {
                uint4 a = *(const uint4*)&A0[gi + (size_t)pr * pstride];
                const unsigned int* ap = (const unsigned int*)&a;
#pragma unroll
                for (int j = 0; j < 4; ++j) {
                    acc8[2 * j]     += bf2f((unsigned short)(ap[j] & 0xFFFF));
                    acc8[2 * j + 1] += bf2f((unsigned short)(ap[j] >> 16));
                }
            }
            float s = invl[p];
            unsigned int w[4];
#pragma unroll
            for (int j = 0; j < 4; ++j)
                w[j] = pack2(acc8[2 * j] * s, acc8[2 * j + 1] * s);
            *(uint4*)&Xt[p * 128 + ((ch ^ (p & 15)) * 8)] = *(uint4*)w;
        }
    }
    __syncthreads();

    // ---- MFMA: wave handles m-tiles {2w, 2w+1} x 4 n-tiles, K=128 ----
    short8 af[2][4];
#pragma unroll
    for (int mi = 0; mi < 2; ++mi)
#pragma unroll
        for (int s = 0; s < 4; ++s)
            af[mi][s] = *(const short8*)
                &Wt[((wave * 2 + mi) * 16 + l16) * 128 + (((4 * s + quad) ^ l16) * 8)];

    f32x4 acc[2][4];
#pragma unroll
    for (int mi = 0; mi < 2; ++mi)
#pragma unroll
        for (int nt = 0; nt < 4; ++nt) acc[mi][nt] = (f32x4){0.f, 0.f, 0.f, 0.f};
#pragma unroll
    for (int nt = 0; nt < 4; ++nt)
#pragma unroll
        for (int s = 0; s < 4; ++s) {
            short8 bf = *(const short8*)
                &Xt[(nt * 16 + l16) * 128 + (((4 * s + quad) ^ l16) * 8)];
            acc[0][nt] = mfma_bf16(af[0][s], bf, acc[0][nt]);
            acc[1][nt] = mfma_bf16(af[1][s], bf, acc[1][nt]);
        }

    // ---- BN + LeakyReLU on C fragments (row o = mt*16+quad*4+r, col l16) ----
    const float BNRS = 0.99999500003749972f;  // 1/sqrt(1 + 1e-5)
#pragma unroll
    for (int mi = 0; mi < 2; ++mi)
#pragma unroll
        for (int r = 0; r < 4; ++r) {
            int o = (wave * 2 + mi) * 16 + quad * 4 + r;
            float sc = jb.G[o] * BNRS, bb = jb.B[o];
#pragma unroll
            for (int nt = 0; nt < 4; ++nt) {
                float y = fmaf(acc[mi][nt][r], sc, bb);
                acc[mi][nt][r] = y > 0.f ? y : 0.1f * y;
            }
        }

    // ---- epilogue ----
    if (jb.out_mode == 0) {
        unsigned short* O = (unsigned short*)jb.out;
        float os = jb.oscale;
#pragma unroll
        for (int mi = 0; mi < 2; ++mi)
#pragma unroll
            for (int nt = 0; nt < 4; ++nt)
#pragma unroll
                for (int r = 0; r < 4; ++r) {
                    int o = (wave * 2 + mi) * 16 + quad * 4 + r;
                    int p = nt * 16 + l16;
                    Ct[p * 128 + (((o >> 3) ^ (p & 15)) * 8) + (o & 7)] =
                        f2bf(acc[mi][nt][r] * os);
                }
        __syncthreads();
#pragma unroll
        for (int i = 0; i < 4; ++i) {
            int idx = t + 256 * i;
            int p = idx >> 4, ch = idx & 15;
            uint4 v = *(const uint4*)&Ct[p * 128 + ((ch ^ (p & 15)) * 8)];
            *(uint4*)&O[((size_t)b * HW_DIM + p0 + p) * C_DIM + ch * 8] = v;
        }
    } else if (jb.out_mode == 1) {
        unsigned short* O = (unsigned short*)jb.out;
#pragma unroll
        for (int mi = 0; mi < 2; ++mi)
#pragma unroll
            for (int nt = 0; nt < 4; ++nt)
#pragma unroll
                for (int r = 0; r < 4; ++r) {
                    int o = (wave * 2 + mi) * 16 + quad * 4 + r;
                    int p = nt * 16 + l16;
                    Ct[o * 64 + (((p >> 3) ^ (o & 7)) * 8) + (p & 7)] =
                        f2bf(acc[mi][nt][r]);
                }
        __syncthreads();
#pragma unroll
        for (int i = 0; i < 4; ++i) {          // all 1024 chunks (r14 fix kept)
            int idx = t + 256 * i;
            int o = idx >> 3, ch = idx & 7;
            uint4 v = *(const uint4*)&Ct[o * 64 + ((ch ^ (o & 7)) * 8)];
            *(uint4*)&O[((size_t)b * C_DIM + o) * HW_DIM + p0 + ch * 8] = v;
        }
    } else {
        float* O = (float*)jb.out;
#pragma unroll
        for (int mi = 0; mi < 2; ++mi)
#pragma unroll
            for (int nt = 0; nt < 4; ++nt)
#pragma unroll
                for (int r = 0; r < 4; ++r) {
                    int o = (wave * 2 + mi) * 16 + quad * 4 + r;
                    size_t g = ((size_t)b * C_DIM + o) * HW_DIM + p0 + nt * 16 + l16;
                    O[g] = acc[mi][nt][r] + jb.resid[g];
                }
    }
}

// ---------------------------------------------------------------------------
// Flash attention (r16): register-lean 4-wave blocks.
//  - 256 thr = 4 waves, each wave rt=2 (32 q-rows); block = 128 q-rows.
//  - Each block owns a full k-slice of its NSPLIT share (no internal group
//    split, no cross-group combine). NIT = (HW/NSPLIT)/64.
//  - K/V staged via global_load_lds (16B) with pre-swizzled per-lane global
//    source + linear LDS dest (same swizzle the ds_reads expect; read path
//    byte-identical to r13/r15). Kills the 32-reg kst/vst prefetch.
//  - Per-wave state ~168 regs (qf 32 + O 64 + S 32 transient + misc) ->
//    __launch_bounds__(256,3): 3 blocks/CU, 24 waves/CU, each SIMD holds
//    3 waves from 3 INDEPENDENT blocks (barriers don't gang them).
//  - LDS 40 KB (Kt 16 + Vt 16 + Plds 8).
// r15 lesson: never cap registers ~100 below need (64-VGPR spill disaster).
// Here the cap (168) matches the counted need; falsifier = FETCH_SIZE>100MB.
// ---------------------------------------------------------------------------
template <int NSPLIT>
__global__ __launch_bounds__(256, 3)
void flash_attn(const unsigned short* __restrict__ Q,
                const unsigned short* __restrict__ K,
                const unsigned short* __restrict__ V,
                unsigned short* __restrict__ Pbase,
                float* __restrict__ Lbase)
{
    __shared__ __align__(16) unsigned short Kt[64 * 128];     // 16 KB
    __shared__ __align__(16) unsigned short Vt[128 * 64];     // 16 KB
    __shared__ __align__(16) unsigned short Plds[4][16][64];  // 8 KB swizzled

    const int t    = threadIdx.x;
    const int wave = t >> 6;
    const int lane = t & 63;
    const int quad = lane >> 4;
    const int l16  = lane & 15;

    constexpr int KS_BITS = (NSPLIT == 8) ? 3 : 2;
    const int bid  = blockIdx.x;
    const int ks   = bid & (NSPLIT - 1);        // = XCD under round-robin
    const int b    = (bid >> KS_BITS) & 1;
    const int qblk = bid >> (KS_BITS + 1);      // 0..47
    const int q0   = qblk * 128 + wave * 32;
    const int kbeg = ks * (HW_DIM / NSPLIT);

    unsigned short* __restrict__ Po = Pbase + (size_t)ks * (2 * HW_DIM * C_DIM);
    float* __restrict__ Lo          = Lbase + (size_t)ks * (2 * HW_DIM);

    const unsigned short* Qb = Q + (size_t)b * HW_DIM * C_DIM;
    const unsigned short* Kb = K + (size_t)b * HW_DIM * C_DIM;
    const unsigned short* Vb = V + (size_t)b * C_DIM * HW_DIM;

    // Q fragments: 2 row-tiles x K=128
    short8 qf[2][4];
#pragma unroll
    for (int rt = 0; rt < 2; ++rt)
#pragma unroll
        for (int s = 0; s < 4; ++s)
            qf[rt][s] = *(const short8*)
                &Qb[(size_t)(q0 + rt * 16 + l16) * C_DIM + s * 32 + quad * 8];

    f32x4 O[2][8];
#pragma unroll
    for (int rt = 0; rt < 2; ++rt)
#pragma unroll
        for (int h = 0; h < 8; ++h) O[rt][h] = (f32x4){0.f, 0.f, 0.f, 0.f};
    float lsum[2][4] = {{0, 0, 0, 0}, {0, 0, 0, 0}};

    // Precomputed swizzled source offsets (ushort units) for staging.
    // K: linear chunk ci -> row=ci>>4, ch=ci&15, src off = row*128+((ch^(row&15))<<3)
    // V: linear chunk ci -> row=ci>>3, ch=ci&7,  src off = row*HW +((ch^(row&7))<<3)
    int koff[4], voff[4];
#pragma unroll
    for (int j = 0; j < 4; ++j) {
        int ci = t + 256 * j;
        int kr = ci >> 4, kc = ci & 15;
        koff[j] = kr * C_DIM + ((kc ^ (kr & 15)) << 3);
        int vr = ci >> 3, vc = ci & 7;
        voff[j] = vr * HW_DIM + ((vc ^ (vr & 7)) << 3);
    }

    const int NIT = (HW_DIM / NSPLIT) / 64;     // 12 (NSPLIT=8) / 24 (=4)
    for (int it = 0; it < NIT; ++it) {
        const int kb = kbeg + it * 64;
        const unsigned short* Ksrc = Kb + (size_t)kb * C_DIM;
        const unsigned short* Vsrc = Vb + kb;
#pragma unroll
        for (int j = 0; j < 4; ++j) {
            int ci = t + 256 * j;
            gload16(Ksrc + koff[j], &Kt[ci * 8]);
            gload16(Vsrc + voff[j], &Vt[ci * 8]);
        }
        __syncthreads();   // drains vmcnt(0): tiles landed; prev reads done

        // ---- QK^T: S[rt][n] over 64 k-cols, K=128 ----
        f32x4 S[2][4];
#pragma unroll
        for (int rt = 0; rt < 2; ++rt)
#pragma unroll
            for (int n = 0; n < 4; ++n) S[rt][n] = (f32x4){0.f, 0.f, 0.f, 0.f};
#pragma unroll
        for (int n = 0; n < 4; ++n)
#pragma unroll
            for (int s = 0; s < 4; ++s) {
                short8 kf = *(const short8*)
                    &Kt[(size_t)(n * 16 + l16) * 128 + (((4 * s + quad) ^ l16) * 8)];
                S[0][n] = mfma_bf16(qf[0][s], kf, S[0][n]);
                S[1][n] = mfma_bf16(qf[1][s], kf, S[1][n]);
            }

        // ---- exp2 -> Plds (swizzled) -> pa fragments ----
        short8 pa[2][2];
#pragma unroll
        for (int rt = 0; rt < 2; ++rt) {
#pragma unroll
            for (int n = 0; n < 4; ++n)
#pragma unroll
                for (int r = 0; r < 4; ++r) {
                    float e = __builtin_amdgcn_exp2f(S[rt][n][r]);
                    lsum[rt][r] += e;
                    int row = quad * 4 + r;
                    Plds[wave][row][(((n * 2 + (l16 >> 3)) ^ (row & 7)) << 3) | (l16 & 7)] =
                        f2bf(e);
                }
            pa[rt][0] = *(const short8*)&Plds[wave][l16][((quad       ^ (l16 & 7)) << 3)];
            pa[rt][1] = *(const short8*)&Plds[wave][l16][(((4 + quad) ^ (l16 & 7)) << 3)];
        }

        // ---- PV ----
        const int m = l16 & 7;
#pragma unroll
        for (int h = 0; h < 8; ++h) {
            short8 v0 = *(const short8*)&Vt[(size_t)(h * 16 + l16) * 64 + ((quad ^ m) * 8)];
            short8 v1 = *(const short8*)&Vt[(size_t)(h * 16 + l16) * 64 + (((quad + 4) ^ m) * 8)];
            O[0][h] = mfma_bf16(pa[0][0], v0, O[0][h]);
            O[0][h] = mfma_bf16(pa[0][1], v1, O[0][h]);
            O[1][h] = mfma_bf16(pa[1][0], v0, O[1][h]);
            O[1][h] = mfma_bf16(pa[1][1], v1, O[1][h]);
        }
        __syncthreads();   // all waves done reading before next overwrite
    }

    // ---- row-sum reduce across 16 cols ----
#pragma unroll
    for (int off = 1; off < 16; off <<= 1)
#pragma unroll
        for (int rt = 0; rt < 2; ++rt)
#pragma unroll
            for (int r = 0; r < 4; ++r)
                lsum[rt][r] += __shfl_xor(lsum[rt][r], off, 64);

    // ---- write P partial + L partial (no cross-group combine needed) ----
#pragma unroll
    for (int rt = 0; rt < 2; ++rt)
#pragma unroll
        for (int r = 0; r < 4; ++r) {
            int lrow = wave * 32 + rt * 16 + quad * 4 + r;
            size_t row = (size_t)b * HW_DIM + qblk * 128 + lrow;
            if (l16 == 0) Lo[row] = lsum[rt][r];
#pragma unroll
            for (int h = 0; h < 8; ++h)
                Po[row * C_DIM + h * 16 + l16] = f2bf(O[rt][h][r]);
        }
}

// ---------------------------------------------------------------------------
extern "C" void kernel_launch(void* const* d_in, const int* in_sizes, int n_in,
                              void* d_out, int out_size, void* d_ws, size_t ws_size,
                              hipStream_t stream)
{
    const float* query = (const float*)d_in[0];
    const float* key   = (const float*)d_in[1];
    const float* q_w1 = (const float*)d_in[2];
    const float* q_g1 = (const float*)d_in[3];
    const float* q_b1 = (const float*)d_in[4];
    const float* q_w2 = (const float*)d_in[5];
    const float* q_g2 = (const float*)d_in[6];
    const float* q_b2 = (const float*)d_in[7];
    const float* k_w1 = (const float*)d_in[8];
    const float* k_g1 = (const float*)d_in[9];
    const float* k_b1 = (const float*)d_in[10];
    const float* k_w2 = (const float*)d_in[11];
    const float* k_g2 = (const float*)d_in[12];
    const float* k_b2 = (const float*)d_in[13];
    const float* v_w  = (const float*)d_in[14];
    const float* v_g  = (const float*)d_in[15];
    const float* v_b  = (const float*)d_in[16];
    const float* o_w  = (const float*)d_in[17];
    const float* o_g  = (const float*)d_in[18];
    const float* o_b  = (const float*)d_in[19];

    // Workspace layout (contiguous):
    //   [ P partials: nsplit x 3145728 B ][ Qbf ][ Kbf ][ Vbf ][ L: nsplit x 49152 B ]
    // nsplit=8 needs 34,996,224 B (proven available in r15); nsplit=4 needs
    // 22,216,704 B (== r13/r14 usage). Qmid/Kmid alias P-partials 0/1.
    const size_t PPART = (size_t)2 * HW_DIM * C_DIM * 2;  // 3,145,728 B
    const size_t LPART = (size_t)2 * HW_DIM * 4;          // 49,152 B
    const int nsplit = (ws_size >= 11 * PPART + 8 * LPART) ? 8 : 4;

    char* ws = (char*)d_ws;
    unsigned short* Pbase = (unsigned short*)ws;
    unsigned short* Qbf = (unsigned short*)(ws + (size_t)nsplit * PPART);
    unsigned short* Kbf = (unsigned short*)(ws + (size_t)nsplit * PPART + PPART);
    unsigned short* Vbf = (unsigned short*)(ws + (size_t)nsplit * PPART + 2 * PPART);
    float*          Lbase = (float*)(ws + (size_t)nsplit * PPART + 3 * PPART);
    unsigned short* Qmid = Pbase;                       // aliases partial 0
    unsigned short* Kmid = Pbase + PPART / 2;           // aliases partial 1
    float* outp = (float*)d_out;

    const float qscale = 0.08838834764831845f * 1.44269504088896340f;

    // Launch A: q-conv1 -> Qmid, k-conv1 -> Kmid, v-conv -> Vbf.
    {
        MJobs J{};
        J.j[0] = {query, nullptr, q_w1, q_g1, q_b1, (void*)Qmid, nullptr, 1.0f, 0, 0, 0};
        J.j[1] = {key,   nullptr, k_w1, k_g1, k_b1, (void*)Kmid, nullptr, 1.0f, 0, 0, 0};
        J.j[2] = {key,   nullptr, v_w,  v_g,  v_b,  (void*)Vbf,  nullptr, 1.0f, 0, 1, 0};
        hipLaunchKernelGGL(conv_mfma, dim3(HW_DIM / 64, 2, 3), dim3(256),
                           0, stream, J);
    }
    // Launch B: q-conv2 -> Qbf (scaled), k-conv2 -> Kbf.
    {
        MJobs J{};
        J.j[0] = {Qmid, nullptr, q_w2, q_g2, q_b2, (void*)Qbf, nullptr, qscale, 1, 0, 0};
        J.j[1] = {Kmid, nullptr, k_w2, k_g2, k_b2, (void*)Kbf, nullptr, 1.0f,   1, 0, 0};
        J.j[2] = J.j[1];
        hipLaunchKernelGGL(conv_mfma, dim3(HW_DIM / 64, 2, 2), dim3(256),
                           0, stream, J);
    }

    // Flash: 4-wave blocks, 128 q-rows each, NSPLIT-way k-split.
    // grid = 2 batches * 48 qblks * nsplit  (768 = 3 blocks/CU at nsplit=8)
    if (nsplit == 8) {
        hipLaunchKernelGGL(HIP_KERNEL_NAME(flash_attn<8>),
                           dim3(2 * (HW_DIM / 128) * 8), dim3(256),
                           0, stream, Qbf, Kbf, Vbf, Pbase, Lbase);
    } else {
        hipLaunchKernelGGL(HIP_KERNEL_NAME(flash_attn<4>),
                           dim3(2 * (HW_DIM / 128) * 4), dim3(256),
                           0, stream, Qbf, Kbf, Vbf, Pbase, Lbase);
    }

    // Launch C: combine nsplit partials -> out-conv + residual.
    {
        MJobs J{};
        J.j[0] = {Pbase, Lbase, o_w, o_g, o_b, (void*)outp, query, 1.0f, 2, 2, nsplit};
        J.j[1] = J.j[0];
        J.j[2] = J.j[0];
        hipLaunchKernelGGL(conv_mfma, dim3(HW_DIM / 64, 2, 1), dim3(256),
                           0, stream, J);
    }
}